// Round 8
// baseline (290.967 us; speedup 1.0000x reference)
//
#include <hip/hip_runtime.h>
#include <hip/hip_bf16.h>

typedef unsigned short u16;
typedef __attribute__((ext_vector_type(8))) short short8;
typedef __attribute__((ext_vector_type(4))) float f32x4;
typedef __attribute__((ext_vector_type(16))) float f32x16;

__device__ inline u16 f2bf(float f) {
  unsigned u = __float_as_uint(f);
  u += 0x7fffu + ((u >> 16) & 1u);   // round-to-nearest-even
  return (u16)(u >> 16);
}

// ---------------- cast fp32 -> bf16 (vectorized x4) ----------------
__global__ __launch_bounds__(256) void cast_kernel(const float* __restrict__ in,
                                                   u16* __restrict__ out, int n4) {
  int i = blockIdx.x * 256 + threadIdx.x;
  if (i >= n4) return;
  float4 v = ((const float4*)in)[i];
  ushort4 o;
  o.x = f2bf(v.x); o.y = f2bf(v.y); o.z = f2bf(v.z); o.w = f2bf(v.w);
  ((ushort4*)out)[i] = o;
}

// ---------------- transpose-cast both weights in one launch ----------------
// blocks x<96: w_qkv [1024][3072] -> [3072][1024]; x>=96: w_proj [1024][1024]
__global__ __launch_bounds__(256) void tcast2_kernel(const float* __restrict__ wqkv,
                                                     const float* __restrict__ wproj,
                                                     u16* __restrict__ oqkv,
                                                     u16* __restrict__ oproj) {
  __shared__ float tile[32][33];
  int bxr = (int)blockIdx.x;
  const float* in = (bxr < 96) ? wqkv : wproj;
  u16* out = (bxr < 96) ? oqkv : oproj;
  int N = (bxr < 96) ? 3072 : 1024;
  int bx = ((bxr < 96) ? bxr : bxr - 96) * 32;
  int by = blockIdx.y * 32;
  int tx = threadIdx.x & 31, ty = threadIdx.x >> 5;
#pragma unroll
  for (int i = 0; i < 4; i++) {
    int r = ty + i * 8;
    tile[r][tx] = in[(size_t)(by + r) * N + bx + tx];
  }
  __syncthreads();
#pragma unroll
  for (int i = 0; i < 4; i++) {
    int r = ty + i * 8;
    out[(size_t)(bx + r) * 1024 + by + tx] = f2bf(tile[tx][r]);
  }
}

// ---------------- fused QKV GEMM + pack ----------------
// C = A[8192][1024] * wqkvT[3072][1024]^T. Q tiles (bn<1024): direct scaled store.
// K/V tiles: pack into attn fragment-major pages via 32KB LDS staging.
// Pack page (bh,kt) = 4096 elems; K: off=(4*(key>>5)+(hd>>4))*512+(key&31)*8
// +((hd>>3)&1)*256+(hd&7); V: same with hd/key swapped. (Inverse of the
// verified pack_kv/attn fragment map.)
__global__ __launch_bounds__(256) void gemm_qkv_fused(const u16* __restrict__ A,
                                                      const u16* __restrict__ Bt,
                                                      u16* __restrict__ qbuf,
                                                      u16* __restrict__ kpack,
                                                      u16* __restrict__ vpack) {
  __shared__ __align__(16) u16 S[16384];  // [0:4096)=As, [4096:8192)=Bs; reused whole as pack staging
  u16* As = S;
  u16* Bs = S + 4096;
  int t = threadIdx.x;
  int wave = t >> 6, lane = t & 63, l15 = lane & 15, quad = lane >> 4;
  int bn = blockIdx.x * 128, bm = blockIdx.y * 128;
  int wm = (wave >> 1) * 64, wn = (wave & 1) * 64;

  f32x4 acc[4][4];
#pragma unroll
  for (int i = 0; i < 4; i++)
#pragma unroll
    for (int j = 0; j < 4; j++) acc[i][j] = (f32x4)0.0f;

  int srow = wave * 16 + (lane >> 2);
  int scol = (lane & 3) * 8;
  const u16* ga0 = A + (size_t)(bm + srow) * 1024 + scol;
  const u16* ga1 = A + (size_t)(bm + 64 + srow) * 1024 + scol;
  const u16* gb0 = Bt + (size_t)(bn + srow) * 1024 + scol;
  const u16* gb1 = Bt + (size_t)(bn + 64 + srow) * 1024 + scol;
  u16* lA0 = As + wave * 512;
  u16* lA1 = As + 2048 + wave * 512;
  u16* lB0 = Bs + wave * 512;
  u16* lB1 = Bs + 2048 + wave * 512;

  for (int k0 = 0; k0 < 1024; k0 += 32) {
    __syncthreads();
    __builtin_amdgcn_global_load_lds((const __attribute__((address_space(1))) unsigned*)(ga0 + k0),
                                     (__attribute__((address_space(3))) unsigned*)lA0, 16, 0, 0);
    __builtin_amdgcn_global_load_lds((const __attribute__((address_space(1))) unsigned*)(ga1 + k0),
                                     (__attribute__((address_space(3))) unsigned*)lA1, 16, 0, 0);
    __builtin_amdgcn_global_load_lds((const __attribute__((address_space(1))) unsigned*)(gb0 + k0),
                                     (__attribute__((address_space(3))) unsigned*)lB0, 16, 0, 0);
    __builtin_amdgcn_global_load_lds((const __attribute__((address_space(1))) unsigned*)(gb1 + k0),
                                     (__attribute__((address_space(3))) unsigned*)lB1, 16, 0, 0);
    __syncthreads();

    short8 a[4], b[4];
#pragma unroll
    for (int mt = 0; mt < 4; mt++)
      a[mt] = *(const short8*)(&As[(wm + mt * 16 + l15) * 32 + quad * 8]);
#pragma unroll
    for (int nt = 0; nt < 4; nt++)
      b[nt] = *(const short8*)(&Bs[(wn + nt * 16 + l15) * 32 + quad * 8]);
#pragma unroll
    for (int mt = 0; mt < 4; mt++)
#pragma unroll
      for (int nt = 0; nt < 4; nt++)
        acc[mt][nt] = __builtin_amdgcn_mfma_f32_16x16x32_bf16(a[mt], b[nt], acc[mt][nt], 0, 0, 0);
  }

  if (bn < 1024) {
    // Q: direct store, pre-scaled by (1/8)*log2(e) for the exp2-domain softmax
    const float SCL = 0.18033688011112f;
#pragma unroll
    for (int mt = 0; mt < 4; mt++)
#pragma unroll
      for (int nt = 0; nt < 4; nt++)
#pragma unroll
        for (int r = 0; r < 4; r++) {
          int row = bm + wm + mt * 16 + quad * 4 + r;
          int col = bn + wn + nt * 16 + l15;
          qbuf[(size_t)row * 1024 + col] = f2bf(acc[mt][nt][r] * SCL);
        }
  } else {
    bool isK = bn < 2048;
    u16* dst = isK ? kpack : vpack;
    int col0 = bn & 1023;
    int b = bm >> 11, kt0 = (bm & 2047) >> 6, h0 = col0 >> 6;

    __syncthreads();  // all waves done with As/Bs -> reuse S as pack staging
    if (isK) {
#pragma unroll
      for (int mt = 0; mt < 4; mt++)
#pragma unroll
        for (int nt = 0; nt < 4; nt++)
#pragma unroll
          for (int r = 0; r < 4; r++) {
            int row = wm + mt * 16 + quad * 4 + r;  // token-in-tile
            int col = wn + nt * 16 + l15;           // col-in-tile
            int key = row & 63, ktl = row >> 6;
            int hd = col & 63, hl = col >> 6;
            int off = (4 * (key >> 5) + (hd >> 4)) * 512 + (key & 31) * 8 +
                      ((hd >> 3) & 1) * 256 + (hd & 7);
            S[(hl * 2 + ktl) * 4096 + off] = f2bf(acc[mt][nt][r]);
          }
    } else {
      // V: the 4 acc regs (rows rowb..rowb+3) map to consecutive e -> b64 write
#pragma unroll
      for (int mt = 0; mt < 4; mt++)
#pragma unroll
        for (int nt = 0; nt < 4; nt++) {
          int rowb = wm + mt * 16 + quad * 4;       // = 0 mod 4, no 8-boundary cross
          int col = wn + nt * 16 + l15;
          int keyb = rowb & 63, ktl = rowb >> 6;
          int hd = col & 63, hl = col >> 6;
          int off = (4 * (hd >> 5) + (keyb >> 4)) * 512 + (hd & 31) * 8 +
                    ((keyb >> 3) & 1) * 256 + (keyb & 7);
          ushort4 w;
          w.x = f2bf(acc[mt][nt][0]);
          w.y = f2bf(acc[mt][nt][1]);
          w.z = f2bf(acc[mt][nt][2]);
          w.w = f2bf(acc[mt][nt][3]);
          *(ushort4*)&S[(hl * 2 + ktl) * 4096 + off] = w;
        }
    }
    __syncthreads();
    // stream staging -> global, coalesced 16B/lane
#pragma unroll
    for (int c = 0; c < 8; c++) {
      int lin = c * 256 + t;       // 2048 chunks of 8 elems
      int page = lin >> 9;         // 512 chunks per page
      int hl = page >> 1, ktl = page & 1;
      size_t pbase = ((size_t)(b * 16 + h0 + hl) * 32 + (kt0 + ktl)) * 4096;
      int off = (lin & 511) * 8;
      *(uint4*)(dst + pbase + off) = *(const uint4*)&S[page * 4096 + off];
    }
  }
}

// ---------------- proj GEMM (m97-style), fp32 out ----------------
__global__ __launch_bounds__(256) void gemm_proj(const u16* __restrict__ A,
                                                 const u16* __restrict__ Bt,
                                                 float* __restrict__ Co) {
  __shared__ __align__(16) u16 As[128 * 32];
  __shared__ __align__(16) u16 Bs[128 * 32];
  int t = threadIdx.x;
  int wave = t >> 6, lane = t & 63, l15 = lane & 15, quad = lane >> 4;
  int bn = blockIdx.x * 128, bm = blockIdx.y * 128;
  int wm = (wave >> 1) * 64, wn = (wave & 1) * 64;

  f32x4 acc[4][4];
#pragma unroll
  for (int i = 0; i < 4; i++)
#pragma unroll
    for (int j = 0; j < 4; j++) acc[i][j] = (f32x4)0.0f;

  int srow = wave * 16 + (lane >> 2);
  int scol = (lane & 3) * 8;
  const u16* ga0 = A + (size_t)(bm + srow) * 1024 + scol;
  const u16* ga1 = A + (size_t)(bm + 64 + srow) * 1024 + scol;
  const u16* gb0 = Bt + (size_t)(bn + srow) * 1024 + scol;
  const u16* gb1 = Bt + (size_t)(bn + 64 + srow) * 1024 + scol;
  u16* lA0 = As + wave * 512;
  u16* lA1 = As + 2048 + wave * 512;
  u16* lB0 = Bs + wave * 512;
  u16* lB1 = Bs + 2048 + wave * 512;

  for (int k0 = 0; k0 < 1024; k0 += 32) {
    __syncthreads();
    __builtin_amdgcn_global_load_lds((const __attribute__((address_space(1))) unsigned*)(ga0 + k0),
                                     (__attribute__((address_space(3))) unsigned*)lA0, 16, 0, 0);
    __builtin_amdgcn_global_load_lds((const __attribute__((address_space(1))) unsigned*)(ga1 + k0),
                                     (__attribute__((address_space(3))) unsigned*)lA1, 16, 0, 0);
    __builtin_amdgcn_global_load_lds((const __attribute__((address_space(1))) unsigned*)(gb0 + k0),
                                     (__attribute__((address_space(3))) unsigned*)lB0, 16, 0, 0);
    __builtin_amdgcn_global_load_lds((const __attribute__((address_space(1))) unsigned*)(gb1 + k0),
                                     (__attribute__((address_space(3))) unsigned*)lB1, 16, 0, 0);
    __syncthreads();

    short8 a[4], b[4];
#pragma unroll
    for (int mt = 0; mt < 4; mt++)
      a[mt] = *(const short8*)(&As[(wm + mt * 16 + l15) * 32 + quad * 8]);
#pragma unroll
    for (int nt = 0; nt < 4; nt++)
      b[nt] = *(const short8*)(&Bs[(wn + nt * 16 + l15) * 32 + quad * 8]);
#pragma unroll
    for (int mt = 0; mt < 4; mt++)
#pragma unroll
      for (int nt = 0; nt < 4; nt++)
        acc[mt][nt] = __builtin_amdgcn_mfma_f32_16x16x32_bf16(a[mt], b[nt], acc[mt][nt], 0, 0, 0);
  }

#pragma unroll
  for (int mt = 0; mt < 4; mt++)
#pragma unroll
    for (int nt = 0; nt < 4; nt++)
#pragma unroll
      for (int r = 0; r < 4; r++) {
        int row = bm + wm + mt * 16 + quad * 4 + r;
        int col = bn + wn + nt * 16 + l15;
        Co[(size_t)row * 1024 + col] = acc[mt][nt][r];
      }
}

// ---------------- flash attention: barrier-free, wave-balanced, max-free ----------
// (unchanged from round 7 — correctness-verified)
__global__ __launch_bounds__(256, 2) void attn_kernel(const u16* __restrict__ qbuf,
                                                      const u16* __restrict__ kpack,
                                                      const u16* __restrict__ vpack,
                                                      u16* __restrict__ ctx) {
  int t = threadIdx.x;
  int wave = t >> 6, lane = t & 63, l31 = lane & 31, hi = lane >> 5;
  int bh = blockIdx.x;
  int s = (int)blockIdx.y * 4 + wave;
  int b = bh >> 4, h = bh & 15;
  int rowbase = b * 2048;
  int hi4 = hi * 4;

  const u16* kp = kpack + (size_t)bh * (32 * 4096) + lane * 8;
  const u16* vp = vpack + (size_t)bh * (32 * 4096) + lane * 8;

#pragma unroll
  for (int ph = 0; ph < 2; ph++) {
    int strip = ph ? 63 - s : s;
    int q0 = strip * 32;
    int q_lane = q0 + l31;

    const u16* qp = qbuf + (size_t)(rowbase + q_lane) * 1024 + h * 64 + hi * 8;
    short8 qf[4];
#pragma unroll
    for (int ks = 0; ks < 4; ks++) qf[ks] = *(const short8*)(qp + ks * 16);

    float l_run = 0.0f;
    f32x16 o[2];
    o[0] = (f32x16)0.0f; o[1] = (f32x16)0.0f;
    int ktmax = (q0 + 31) >> 6;

    for (int kt = 0; kt <= ktmax; kt++) {
      const u16* kb = kp + kt * 4096;
      const u16* vb = vp + kt * 4096;

      short8 ka[8], vv[8];
#pragma unroll
      for (int j = 0; j < 8; j++) {
        ka[j] = *(const short8*)(kb + j * 512);
        vv[j] = *(const short8*)(vb + j * 512);
      }

      f32x16 st0 = (f32x16)0.0f, st1 = (f32x16)0.0f;
#pragma unroll
      for (int ks = 0; ks < 4; ks++) {
        st0 = __builtin_amdgcn_mfma_f32_32x32x16_bf16(ka[ks], qf[ks], st0, 0, 0, 0);
        st1 = __builtin_amdgcn_mfma_f32_32x32x16_bf16(ka[4 + ks], qf[ks], st1, 0, 0, 0);
      }

      unsigned pk[2][8];
      if (kt == ktmax) {
#pragma unroll
        for (int ii = 0; ii < 8; ii++) {
          int key = kt * 64 + ((2 * ii) & 3) + 8 * ((2 * ii) >> 2) + hi4;
          float p00 = (key <= q_lane) ? __builtin_amdgcn_exp2f(st0[2 * ii]) : 0.0f;
          float p01 = (key + 1 <= q_lane) ? __builtin_amdgcn_exp2f(st0[2 * ii + 1]) : 0.0f;
          float p10 = (key + 32 <= q_lane) ? __builtin_amdgcn_exp2f(st1[2 * ii]) : 0.0f;
          float p11 = (key + 33 <= q_lane) ? __builtin_amdgcn_exp2f(st1[2 * ii + 1]) : 0.0f;
          l_run += p00 + p01 + p10 + p11;
          pk[0][ii] = ((__float_as_uint(p00) + 0x8000u) >> 16) |
                      ((__float_as_uint(p01) + 0x8000u) & 0xffff0000u);
          pk[1][ii] = ((__float_as_uint(p10) + 0x8000u) >> 16) |
                      ((__float_as_uint(p11) + 0x8000u) & 0xffff0000u);
        }
      } else {
#pragma unroll
        for (int ii = 0; ii < 8; ii++) {
          float p00 = __builtin_amdgcn_exp2f(st0[2 * ii]);
          float p01 = __builtin_amdgcn_exp2f(st0[2 * ii + 1]);
          float p10 = __builtin_amdgcn_exp2f(st1[2 * ii]);
          float p11 = __builtin_amdgcn_exp2f(st1[2 * ii + 1]);
          l_run += p00 + p01 + p10 + p11;
          pk[0][ii] = ((__float_as_uint(p00) + 0x8000u) >> 16) |
                      ((__float_as_uint(p01) + 0x8000u) & 0xffff0000u);
          pk[1][ii] = ((__float_as_uint(p10) + 0x8000u) >> 16) |
                      ((__float_as_uint(p11) + 0x8000u) & 0xffff0000u);
        }
      }

      short8 pf[4];
#pragma unroll
      for (int ks2 = 0; ks2 < 4; ks2++) {
        int km = ks2 >> 1, h4 = (ks2 & 1) * 4;
        unsigned A0 = pk[km][h4 + 0], A1 = pk[km][h4 + 1];
        unsigned B0 = pk[km][h4 + 2], B1 = pk[km][h4 + 3];
        unsigned tA0 = (unsigned)__shfl_xor((int)A0, 32);
        unsigned tA1 = (unsigned)__shfl_xor((int)A1, 32);
        unsigned tB0 = (unsigned)__shfl_xor((int)B0, 32);
        unsigned tB1 = (unsigned)__shfl_xor((int)B1, 32);
        union { unsigned u[4]; short8 sh; } fr;
        fr.u[0] = hi ? tB0 : A0;
        fr.u[1] = hi ? tB1 : A1;
        fr.u[2] = hi ? B0 : tA0;
        fr.u[3] = hi ? B1 : tA1;
        pf[ks2] = fr.sh;
      }

#pragma unroll
      for (int am = 0; am < 2; am++)
#pragma unroll
        for (int ks2 = 0; ks2 < 4; ks2++)
          o[am] = __builtin_amdgcn_mfma_f32_32x32x16_bf16(vv[am * 4 + ks2], pf[ks2], o[am], 0, 0, 0);
    }

    float l_tot = l_run + __shfl_xor(l_run, 32);
    float inv = 1.0f / l_tot;
    size_t obase = (size_t)(rowbase + q_lane) * 1024 + h * 64;
#pragma unroll
    for (int am = 0; am < 2; am++)
#pragma unroll
      for (int k = 0; k < 4; k++) {
        ushort4 w;
        w.x = f2bf(o[am][4 * k + 0] * inv);
        w.y = f2bf(o[am][4 * k + 1] * inv);
        w.z = f2bf(o[am][4 * k + 2] * inv);
        w.w = f2bf(o[am][4 * k + 3] * inv);
        *(ushort4*)&ctx[obase + am * 32 + k * 8 + hi4] = w;
      }
  }
}

// ---------------- launch ----------------
// ws layout (72 MB):
//   0-16 qbuf | 16-32 kpack | 32-48 vpack | 48-64 xb->ctx | 64-70 wqkvT | 70-72 wprojT
extern "C" void kernel_launch(void* const* d_in, const int* in_sizes, int n_in,
                              void* d_out, int out_size, void* d_ws, size_t ws_size,
                              hipStream_t stream) {
  const float* x      = (const float*)d_in[0];
  const float* w_qkv  = (const float*)d_in[1];
  const float* w_proj = (const float*)d_in[2];
  float* out = (float*)d_out;

  char* ws = (char*)d_ws;
  const size_t MB = 1024 * 1024;
  u16* qbuf   = (u16*)(ws);
  u16* kpack  = (u16*)(ws + 16 * MB);
  u16* vpack  = (u16*)(ws + 32 * MB);
  u16* xb     = (u16*)(ws + 48 * MB);
  u16* wqkvT  = (u16*)(ws + 64 * MB);
  u16* wprojT = (u16*)(ws + 70 * MB);
  u16* ctx    = xb;  // xb dead after gemm_qkv_fused

  cast_kernel<<<8192, 256, 0, stream>>>(x, xb, 2097152);
  tcast2_kernel<<<dim3(128, 32), 256, 0, stream>>>(w_qkv, w_proj, wqkvT, wprojT);
  gemm_qkv_fused<<<dim3(24, 64), 256, 0, stream>>>(xb, wqkvT, qbuf, kpack, vpack);
  attn_kernel<<<dim3(64, 8), 256, 0, stream>>>(qbuf, kpack, vpack, ctx);
  gemm_proj<<<dim3(8, 64), 256, 0, stream>>>(ctx, wprojT, out);
}